// Round 7
// baseline (60.952 us; speedup 1.0000x reference)
//
#include <hip/hip_runtime.h>

#define N 192
#define G5ROW (1338 * 32)     // 42816 ushorts per global-y row (6 db * 223 slots * 32)
#define CCHUNK 8              // c columns per s1 block (B-frag reuse)
#define NCHUNK 28             // ceil(223 / CCHUNK)
#define PITCH 34              // s2 LDS slot pitch in ushorts (68 B, dword aligned)
#define REG (64 * PITCH)      // ushorts per (buf,yl) region = 2176

typedef __attribute__((ext_vector_type(8))) short short8;   // 8 bf16
typedef __attribute__((ext_vector_type(4))) float f32x4;

static __device__ __forceinline__ unsigned short f2bf(float x) {
    uint32_t u = __builtin_bit_cast(uint32_t, x);
    u += 0x7FFFu + ((u >> 16) & 1u);          // RNE (inputs finite)
    return (unsigned short)(u >> 16);
}

// packed (bf16 Ar, bf16 -Ai) for A[i][c]; zero pad outside 383x383.
// Identical math to the old prep kernel: amp = z/(r2+z^2), ph = (2pi/0.5)*R.
static __device__ __forceinline__ uint32_t apack(int i, int c, float z) {
    if (i >= 383 || c >= 383) return 0u;
    const float X0 = 191.00005f;              // 0.5*(2*192 + 1e-4) - 1
    float xr = (float)i - X0;
    float yc = (float)c - X0;
    float r2 = xr * xr + yc * yc;
    float R2 = r2 + z * z;
    float R  = sqrtf(R2);
    float amp = z / R2;
    float ph = 12.566371f * R;
    float sv, cv;
    sincosf(ph, &sv, &cv);
    return (uint32_t)f2bf(amp * cv) | ((uint32_t)f2bf(-amp * sv) << 16);
}

// ---------------------------------------------------------------------------
// prep: Wt[dx][dy] = packed (bf16 Wr, bf16 Wi), transposed field. Tiny.
// ---------------------------------------------------------------------------
__global__ __launch_bounds__(256) void prepw_kernel(const float* __restrict__ fr,
                                                    const float* __restrict__ fi,
                                                    uint32_t* __restrict__ Wt) {
    int idx = blockIdx.x * 256 + threadIdx.x;
    if (idx < N * N) {
        int dy = idx / N, dx = idx - dy * N;
        Wt[dx * N + dy] = (uint32_t)f2bf(fr[idx]) | ((uint32_t)f2bf(fi[idx]) << 16);
    }
}

// ---------------------------------------------------------------------------
// stage 1: G[c][y][dx] = sum_dy Ar[y+dy][c]*Wr[dy][dx] - Ai[y+dy][c]*Wi[dy][dx]
// via mfma_f32_16x16x32_bf16, K=384 (dy x re/im interleaved).
// Block = (db, chunk of 8 c's, y-third of 64 rows), 4 waves = 4 y-tiles.
// B-frags loaded ONCE per block. A columns GENERATED in-kernel (sincos) into
// a double-buffered LDS column of duplicated 8B pairs; gen of c+1 overlaps
// MFMA of c on the separate VALU pipe. G5 rows are GLOBAL y.
// ---------------------------------------------------------------------------
__global__ __launch_bounds__(256) void s1_kernel(const float* __restrict__ zp,
                                                 const uint32_t* __restrict__ Wt,
                                                 unsigned short* __restrict__ G5) {
    __shared__ uint2 colAd[2][384];           // 6 KB double buffer

    const int tid  = threadIdx.x;
    const int l    = tid & 63;
    const int w    = tid >> 6;                // wave -> y-tile within third
    const int db   = blockIdx.x / NCHUNK;
    const int ck   = blockIdx.x - db * NCHUNK;
    const int ci0  = ck * CCHUNK;
    const int dx0  = db * 32;
    const int yoff = blockIdx.y * 64;
    const int m    = l & 15;
    const int kg   = l >> 4;
    const float z  = zp[0];

    // B fragments: loaded once, live in registers for all 8 c's.
    uint4 bfr[2][12];
    #pragma unroll
    for (int t = 0; t < 2; ++t) {
        int dx = dx0 + t * 16 + m;
        #pragma unroll
        for (int ks = 0; ks < 12; ++ks)
            bfr[t][ks] = *(const uint4*)(Wt + dx * N + ks * 16 + kg * 4);
    }

    // generate first column into buffer 0
    {
        int c0 = dx0 + ci0;
        for (int i = tid; i < 384; i += 256)
            colAd[0][i] = make_uint2(apack(i, c0, z), apack(i + 1, c0, z));
    }
    __syncthreads();

    for (int q = 0; q < CCHUNK; ++q) {
        const int ci  = ci0 + q;
        const int cur = q & 1;
        // generate next column into the other buffer (overlaps MFMA below)
        if (q < CCHUNK - 1) {
            int cn = dx0 + ci + 1;            // <= 383 (apack pads with 0)
            for (int i = tid; i < 384; i += 256)
                colAd[cur ^ 1][i] = make_uint2(apack(i, cn, z), apack(i + 1, cn, z));
        }

        f32x4 acc0 = {0.f, 0.f, 0.f, 0.f};
        f32x4 acc1 = {0.f, 0.f, 0.f, 0.f};
        const int srow = yoff + w * 16 + m;
        #pragma unroll
        for (int ks = 0; ks < 12; ++ks) {
            int s = srow + ks * 16 + kg * 4;          // <= 379
            uint2 a0 = colAd[cur][s];                 // pairs s, s+1
            uint2 a1 = colAd[cur][s + 2];             // pairs s+2, s+3
            union { uint32_t u[4]; short8 v; } af;
            af.u[0] = a0.x; af.u[1] = a0.y; af.u[2] = a1.x; af.u[3] = a1.y;
            union { uint4 q4; short8 v; } b0, b1;
            b0.q4 = bfr[0][ks]; b1.q4 = bfr[1][ks];
            acc0 = __builtin_amdgcn_mfma_f32_16x16x32_bf16(af.v, b0.v, acc0, 0, 0, 0);
            acc1 = __builtin_amdgcn_mfma_f32_16x16x32_bf16(af.v, b1.v, acc1, 0, 0, 0);
        }

        if (ci < 223) {                       // guard chunk tail (ci==223 pad)
            const int slot  = db * 223 + ci;
            const int y_loc = yoff + w * 16 + kg * 4;     // global y
            #pragma unroll
            for (int r = 0; r < 4; ++r) {
                size_t row = (size_t)(y_loc + r) * G5ROW + (size_t)slot * 32;
                G5[row + m]      = f2bf(acc0[r]);
                G5[row + 16 + m] = f2bf(acc1[r]);
            }
        }
        __syncthreads();   // next iter reads the buffer generated this iter
    }
}

// ---------------------------------------------------------------------------
// stage 2: out[y][x] = sum_dx G[x+dx][y][dx], flip fused into the store.
// Block = 32 x * 2 y (64 thr). db-loop with double-buffered 4.3 KB stages
// (17.4 KB LDS -> 9 blocks/CU). Slot pitch 34 ushorts -> anti-diagonal read
// hits 32 distinct banks (17 coprime 32). Staging: coalesced dword loads +
// aligned ds_write_b32, conflict-free.
// ---------------------------------------------------------------------------
__global__ __launch_bounds__(64) void s2_kernel(const unsigned short* __restrict__ G5,
                                                float* __restrict__ out) {
    __shared__ __align__(16) unsigned short lds[2][2][REG];   // 17408 B

    const int tid = threadIdx.x;
    const int x0  = blockIdx.x * 32;
    const int y0  = blockIdx.y * 2;           // global y
    const int x_l = tid & 31;
    const int yl  = tid >> 5;

    // stage db-window into buf: per yl, 63 slots * 32 elems = 1008 dwords
#define STAGE(buf, db)                                                         \
    {                                                                          \
        const uint32_t* s0 = (const uint32_t*)(G5 + (size_t)y0 * G5ROW         \
                                             + (size_t)((db) * 223 + x0) * 32);\
        const uint32_t* s1p = (const uint32_t*)(G5 + (size_t)(y0 + 1) * G5ROW  \
                                             + (size_t)((db) * 223 + x0) * 32);\
        for (int u = tid; u < 2016; u += 64) {                                 \
            int y  = u / 1008;                                                 \
            int d  = u - y * 1008;                                             \
            int s  = d >> 4, ep = d & 15;                                      \
            uint32_t v = (y ? s1p : s0)[d];                                    \
            *(uint32_t*)&lds[buf][y][s * PITCH + ep * 2] = v;                  \
        }                                                                      \
    }

    float sum = 0.f;
    STAGE(0, 0)
    __syncthreads();
    for (int db = 0; db < 6; ++db) {
        const int buf = db & 1;
        if (db < 5) STAGE(buf ^ 1, db + 1)
        const unsigned short* __restrict__ L = lds[buf][yl];
        #pragma unroll
        for (int j = 0; j < 32; ++j) {        // local slot = x_l + j, elem j
            sum += __builtin_bit_cast(float,
                       (uint32_t)L[(x_l + j) * PITCH + j] << 16);
        }
        __syncthreads();
    }
#undef STAGE

    int y = y0 + yl, x = x0 + x_l;
    out[(191 - y) * N + (191 - x)] = sum;
}

extern "C" void kernel_launch(void* const* d_in, const int* in_sizes, int n_in,
                              void* d_out, int out_size, void* d_ws, size_t ws_size,
                              hipStream_t stream) {
    const float* fr = (const float*)d_in[0];
    const float* fi = (const float*)d_in[1];
    const float* zp = (const float*)d_in[2];

    uint32_t* Wt = (uint32_t*)d_ws;                        // 192*192 u32 = 144 KB
    unsigned short* G5 = (unsigned short*)(Wt + N * N);    // 192*42816 u16 = 16.4 MB

    prepw_kernel<<<(N * N + 255) / 256, 256, 0, stream>>>(fr, fi, Wt);
    s1_kernel<<<dim3(6 * NCHUNK, 3), 256, 0, stream>>>(zp, Wt, G5);
    s2_kernel<<<dim3(6, 96), 64, 0, stream>>>(G5, (float*)d_out);
}

// Round 8
// 30.610 us; speedup vs baseline: 1.9913x; 1.9913x over previous
//
#include <hip/hip_runtime.h>

#define N 192
#define CCHUNK 8              // c columns per s1 block (B-frag reuse)
#define NCHUNK 28             // 224 / 8 chunks of c per db
#define XT 39                 // x-tile width per block (32 + CCHUNK - 1)
#define XP 41                 // x-tile LDS pitch (f32) - conflict spreading

typedef __attribute__((ext_vector_type(8))) short short8;   // 8 bf16
typedef __attribute__((ext_vector_type(4))) float f32x4;

static __device__ __forceinline__ unsigned short f2bf(float x) {
    uint32_t u = __builtin_bit_cast(uint32_t, x);
    u += 0x7FFFu + ((u >> 16) & 1u);          // RNE (inputs finite)
    return (unsigned short)(u >> 16);
}

// ---------------------------------------------------------------------------
// prep: Abf[r][c] 384x384 packed (bf16 Ar, bf16 -Ai), zero-padded row/col 383;
//       Wt[dx][dy] packed (bf16 Wr, bf16 Wi); zero the P partial planes.
// amp = cos(atan2(rho,z))/R = z/(r2+z^2); ph = (2pi/0.5)*R.
// ---------------------------------------------------------------------------
__global__ __launch_bounds__(256) void prep_kernel(const float* __restrict__ fr,
                                                   const float* __restrict__ fi,
                                                   const float* __restrict__ zp,
                                                   uint32_t* __restrict__ Abf,
                                                   uint32_t* __restrict__ Wt,
                                                   float* __restrict__ P) {
    int idx = blockIdx.x * 256 + threadIdx.x;
    float z = zp[0];
    if (idx < 384 * 384) {
        int r = idx / 384, c = idx - r * 384;
        uint32_t pack = 0u;
        if (r < 383 && c < 383) {
            const float X0 = 191.00005f;      // 0.5*(2*192 + 1e-4) - 1
            float xr = (float)r - X0;
            float yc = (float)c - X0;
            float r2 = xr * xr + yc * yc;
            float R2 = r2 + z * z;
            float R  = sqrtf(R2);
            float amp = z / R2;
            float ph = 12.566371f * R;        // 2*pi/0.5
            float sv, cv;
            sincosf(ph, &sv, &cv);
            pack = (uint32_t)f2bf(amp * cv) | ((uint32_t)f2bf(-amp * sv) << 16);
        }
        Abf[idx] = pack;
    }
    if (idx < N * N) {
        int dy = idx / N, dx = idx - dy * N;
        Wt[dx * N + dy] = (uint32_t)f2bf(fr[idx]) | ((uint32_t)f2bf(fi[idx]) << 16);
    }
    if (idx < 6 * N * N) P[idx] = 0.f;        // zero partials every call
}

// ---------------------------------------------------------------------------
// stage 1: G[c][y][dx] = sum_dy Ar[y+dy][c]*Wr[dy][dx] - Ai[y+dy][c]*Wi[dy][dx]
// via mfma_f32_16x16x32_bf16 (K=384, dy x re/im interleaved), then the dx-sum
// folded IN-BLOCK: out[y][x=c-dx] accumulated into LDS f32 tile outT[64][39]
// (x = ci - m for acc0, ci - 16 - m for acc1), flushed once per block with
// atomicAdd into P[db]. No giant G intermediate.
// Block = (db, chunk of 8 c's, y-third of 64 rows), 4 waves = 4 y-tiles.
// ---------------------------------------------------------------------------
__global__ __launch_bounds__(256) void s1_kernel(const uint32_t* __restrict__ Abf,
                                                 const uint32_t* __restrict__ Wt,
                                                 float* __restrict__ P) {
    __shared__ uint2 colAd[2][384];           // 6 KB A-column double buffer
    __shared__ float outT[64 * XP];           // 10.5 KB per-block output tile

    const int tid  = threadIdx.x;
    const int l    = tid & 63;
    const int w    = tid >> 6;                // wave -> y-tile within third
    const int db   = blockIdx.x / NCHUNK;
    const int ck   = blockIdx.x - db * NCHUNK;
    const int ci0  = ck * CCHUNK;
    const int dx0  = db * 32;
    const int yoff = blockIdx.y * 64;
    const int m    = l & 15;
    const int kg   = l >> 4;

    // B fragments: loaded once, live in registers for all 8 c's.
    uint4 bfr[2][12];
    #pragma unroll
    for (int t = 0; t < 2; ++t) {
        int dx = dx0 + t * 16 + m;
        #pragma unroll
        for (int ks = 0; ks < 12; ++ks)
            bfr[t][ks] = *(const uint4*)(Wt + dx * N + ks * 16 + kg * 4);
    }

    // zero the output tile
    for (int e = tid; e < 64 * XP; e += 256) outT[e] = 0.f;

    // stage first column (row c0 of Abf; A symmetric so row c == col c)
    {
        int c0 = dx0 + ci0;
        for (int i = tid; i < 383; i += 256) {
            uint32_t v0 = Abf[c0 * 384 + i];
            uint32_t v1 = (i < 382) ? Abf[c0 * 384 + i + 1] : 0u;
            colAd[0][i] = make_uint2(v0, v1);
        }
    }
    __syncthreads();

    for (int q = 0; q < CCHUNK; ++q) {
        const int ci  = ci0 + q;
        const int cur = q & 1;
        // prefetch next column into the other buffer
        if (q < CCHUNK - 1) {
            int cn = dx0 + ci + 1;            // <= 383 (zero-padded)
            for (int i = tid; i < 383; i += 256) {
                uint32_t v0 = Abf[cn * 384 + i];
                uint32_t v1 = (i < 382) ? Abf[cn * 384 + i + 1] : 0u;
                colAd[cur ^ 1][i] = make_uint2(v0, v1);
            }
        }

        f32x4 acc0 = {0.f, 0.f, 0.f, 0.f};
        f32x4 acc1 = {0.f, 0.f, 0.f, 0.f};
        const int srow = yoff + w * 16 + m;
        #pragma unroll
        for (int ks = 0; ks < 12; ++ks) {
            int s = srow + ks * 16 + kg * 4;          // <= 379
            uint2 a0 = colAd[cur][s];                 // pairs s, s+1
            uint2 a1 = colAd[cur][s + 2];             // pairs s+2, s+3
            union { uint32_t u[4]; short8 v; } af;
            af.u[0] = a0.x; af.u[1] = a0.y; af.u[2] = a1.x; af.u[3] = a1.y;
            union { uint4 q4; short8 v; } b0, b1;
            b0.q4 = bfr[0][ks]; b1.q4 = bfr[1][ks];
            acc0 = __builtin_amdgcn_mfma_f32_16x16x32_bf16(af.v, b0.v, acc0, 0, 0, 0);
            acc1 = __builtin_amdgcn_mfma_f32_16x16x32_bf16(af.v, b1.v, acc1, 0, 0, 0);
        }

        // fold dx-contraction: lane m holds dx0+m (acc0), dx0+16+m (acc1);
        // x = c - dx -> xt = (q+31) - m  and  (q+15) - m, all in [0, 39).
        // Rows disjoint per (w, kg) -> no inter-lane/inter-wave races.
        if (ci < 223) {
            const int xb = q + 31;
            #pragma unroll
            for (int r = 0; r < 4; ++r) {
                int row = w * 16 + kg * 4 + r;
                outT[row * XP + xb - m]      += acc0[r];
                outT[row * XP + xb - 16 - m] += acc1[r];
            }
        }
        __syncthreads();   // next iter reads the buffer staged this iter
    }

    // flush: outT -> P[db] (global atomics; ~5 contributors per element)
    const int xg0 = ci0 - 31;
    for (int e = tid; e < 64 * XT; e += 256) {
        int row = e / XT, xt = e - row * XT;
        int x = xg0 + xt;
        if (x >= 0 && x < N)
            atomicAdd(&P[db * (N * N) + (yoff + row) * N + x], outT[row * XP + xt]);
    }
}

// ---------------------------------------------------------------------------
// stage 3: out[y][x] = sum_db P[db][y][x], flip fused into the store.
// ---------------------------------------------------------------------------
__global__ __launch_bounds__(256) void s3_kernel(const float* __restrict__ P,
                                                 float* __restrict__ out) {
    int idx = blockIdx.x * 256 + threadIdx.x;   // < N*N
    int y = idx / N;
    int x = idx - y * N;
    float s = 0.f;
    #pragma unroll
    for (int db = 0; db < 6; ++db) s += P[db * (N * N) + idx];
    out[(191 - y) * N + (191 - x)] = s;
}

extern "C" void kernel_launch(void* const* d_in, const int* in_sizes, int n_in,
                              void* d_out, int out_size, void* d_ws, size_t ws_size,
                              hipStream_t stream) {
    const float* fr = (const float*)d_in[0];
    const float* fi = (const float*)d_in[1];
    const float* zp = (const float*)d_in[2];

    uint32_t* Abf = (uint32_t*)d_ws;                   // 384*384 u32 = 576 KB
    uint32_t* Wt  = Abf + 384 * 384;                   // 192*192 u32 = 144 KB
    float*    P   = (float*)(Wt + N * N);              // 6*192*192 f32 = 884 KB
    // total ws ~1.6 MB

    prep_kernel<<<864, 256, 0, stream>>>(fr, fi, zp, Abf, Wt, P);
    s1_kernel<<<dim3(6 * NCHUNK, 3), 256, 0, stream>>>(Abf, Wt, P);
    s3_kernel<<<(N * N + 255) / 256, 256, 0, stream>>>(P, (float*)d_out);
}

// Round 9
// 29.618 us; speedup vs baseline: 2.0580x; 1.0335x over previous
//
#include <hip/hip_runtime.h>

#define N 192
#define CCHUNK 8              // c columns per s1 block (B-frag reuse)
#define NCHUNK 28             // 224 / 8 chunks of c per db
#define XT 39                 // x-tile width per block (32 + CCHUNK - 1)
#define XP 41                 // x-tile LDS pitch (f32) - conflict spreading

typedef __attribute__((ext_vector_type(8))) short short8;   // 8 bf16
typedef __attribute__((ext_vector_type(4))) float f32x4;

static __device__ __forceinline__ unsigned short f2bf(float x) {
    uint32_t u = __builtin_bit_cast(uint32_t, x);
    u += 0x7FFFu + ((u >> 16) & 1u);          // RNE (inputs finite)
    return (unsigned short)(u >> 16);
}

// ---------------------------------------------------------------------------
// prep: Abf[r][c] 384x384 packed (bf16 Ar, bf16 -Ai), zero-padded row/col 383;
//       Wt[dx][dy] packed (bf16 Wr, bf16 Wi); zero d_out (atomic target).
// amp = cos(atan2(rho,z))/R = z/(r2+z^2); ph = (2pi/0.5)*R.
// ---------------------------------------------------------------------------
__global__ __launch_bounds__(256) void prep_kernel(const float* __restrict__ fr,
                                                   const float* __restrict__ fi,
                                                   const float* __restrict__ zp,
                                                   uint32_t* __restrict__ Abf,
                                                   uint32_t* __restrict__ Wt,
                                                   float* __restrict__ out) {
    int idx = blockIdx.x * 256 + threadIdx.x;
    float z = zp[0];
    if (idx < 384 * 384) {
        int r = idx / 384, c = idx - r * 384;
        uint32_t pack = 0u;
        if (r < 383 && c < 383) {
            const float X0 = 191.00005f;      // 0.5*(2*192 + 1e-4) - 1
            float xr = (float)r - X0;
            float yc = (float)c - X0;
            float r2 = xr * xr + yc * yc;
            float R2 = r2 + z * z;
            float R  = sqrtf(R2);
            float amp = z / R2;
            float ph = 12.566371f * R;        // 2*pi/0.5
            float sv, cv;
            sincosf(ph, &sv, &cv);
            pack = (uint32_t)f2bf(amp * cv) | ((uint32_t)f2bf(-amp * sv) << 16);
        }
        Abf[idx] = pack;
    }
    if (idx < N * N) {
        int dy = idx / N, dx = idx - dy * N;
        Wt[dx * N + dy] = (uint32_t)f2bf(fr[idx]) | ((uint32_t)f2bf(fi[idx]) << 16);
        out[idx] = 0.f;                       // zero the atomic target each call
    }
}

// ---------------------------------------------------------------------------
// stage 1: G[c][y][dx] = sum_dy Ar[y+dy][c]*Wr[dy][dx] - Ai[y+dy][c]*Wi[dy][dx]
// via mfma_f32_16x16x32_bf16 (K=384, dy x re/im interleaved); dx-contraction
// folded in-block into LDS f32 tile outT[64][39] (x = c - dx), flushed once
// per block with atomicAdd DIRECTLY into flipped d_out.
// A column staged as 16B-aligned QUADS (elems i..i+3 at slot i) -> one
// ds_read_b128 per k-step instead of 2x ds_read_b64.
// Block = (db, chunk of 8 c's, y-third of 64 rows), 4 waves = 4 y-tiles.
// ---------------------------------------------------------------------------
__global__ __launch_bounds__(256) void s1_kernel(const uint32_t* __restrict__ Abf,
                                                 const uint32_t* __restrict__ Wt,
                                                 float* __restrict__ out) {
    __shared__ uint4 colAq[2][384];           // 12 KB A-column double buffer
    __shared__ float outT[64 * XP];           // 10.5 KB per-block output tile

    const int tid  = threadIdx.x;
    const int l    = tid & 63;
    const int w    = tid >> 6;                // wave -> y-tile within third
    const int db   = blockIdx.x / NCHUNK;
    const int ck   = blockIdx.x - db * NCHUNK;
    const int ci0  = ck * CCHUNK;
    const int dx0  = db * 32;
    const int yoff = blockIdx.y * 64;
    const int m    = l & 15;
    const int kg   = l >> 4;

    // B fragments: loaded once, live in registers for all 8 c's.
    uint4 bfr[2][12];
    #pragma unroll
    for (int t = 0; t < 2; ++t) {
        int dx = dx0 + t * 16 + m;
        #pragma unroll
        for (int ks = 0; ks < 12; ++ks)
            bfr[t][ks] = *(const uint4*)(Wt + dx * N + ks * 16 + kg * 4);
    }

    // zero the output tile
    for (int e = tid; e < 64 * XP; e += 256) outT[e] = 0.f;

    // stage first column as quads (row c0 of Abf; A symmetric: row c == col c)
    {
        int c0 = dx0 + ci0;
        const uint32_t* ar = Abf + c0 * 384;
        for (int i = tid; i < 384; i += 256) {
            uint32_t e0 = ar[i];
            uint32_t e1 = (i < 383) ? ar[i + 1] : 0u;
            uint32_t e2 = (i < 382) ? ar[i + 2] : 0u;
            uint32_t e3 = (i < 381) ? ar[i + 3] : 0u;
            colAq[0][i] = make_uint4(e0, e1, e2, e3);
        }
    }
    __syncthreads();

    for (int q = 0; q < CCHUNK; ++q) {
        const int ci  = ci0 + q;
        const int cur = q & 1;
        // prefetch next column into the other buffer
        if (q < CCHUNK - 1) {
            int cn = dx0 + ci + 1;            // <= 383 (zero-padded row)
            const uint32_t* ar = Abf + cn * 384;
            for (int i = tid; i < 384; i += 256) {
                uint32_t e0 = ar[i];
                uint32_t e1 = (i < 383) ? ar[i + 1] : 0u;
                uint32_t e2 = (i < 382) ? ar[i + 2] : 0u;
                uint32_t e3 = (i < 381) ? ar[i + 3] : 0u;
                colAq[cur ^ 1][i] = make_uint4(e0, e1, e2, e3);
            }
        }

        f32x4 acc0 = {0.f, 0.f, 0.f, 0.f};
        f32x4 acc1 = {0.f, 0.f, 0.f, 0.f};
        const int srow = yoff + w * 16 + m;
        #pragma unroll
        for (int ks = 0; ks < 12; ++ks) {
            int s = srow + ks * 16 + kg * 4;          // <= 379
            uint4 aq = colAq[cur][s];                 // elems s..s+3, one b128
            union { uint4 q4; short8 v; } af, b0, b1;
            af.q4 = aq;
            b0.q4 = bfr[0][ks]; b1.q4 = bfr[1][ks];
            acc0 = __builtin_amdgcn_mfma_f32_16x16x32_bf16(af.v, b0.v, acc0, 0, 0, 0);
            acc1 = __builtin_amdgcn_mfma_f32_16x16x32_bf16(af.v, b1.v, acc1, 0, 0, 0);
        }

        // fold dx-contraction: lane m holds dx0+m (acc0), dx0+16+m (acc1);
        // x = c - dx -> xt = (q+31) - m  and  (q+15) - m, all in [0, 39).
        // Rows disjoint per (w, kg) -> no inter-lane/inter-wave races.
        if (ci < 223) {
            const int xb = q + 31;
            #pragma unroll
            for (int r = 0; r < 4; ++r) {
                int row = w * 16 + kg * 4 + r;
                outT[row * XP + xb - m]      += acc0[r];
                outT[row * XP + xb - 16 - m] += acc1[r];
            }
        }
        __syncthreads();   // next iter reads the buffer staged this iter
    }

    // flush: outT -> flipped d_out (global atomics; ~26 contributors/element)
    const int xg0 = ci0 - 31;
    for (int e = tid; e < 64 * XT; e += 256) {
        int row = e / XT, xt = e - row * XT;
        int x = xg0 + xt;
        if (x >= 0 && x < N) {
            int y = yoff + row;
            atomicAdd(&out[(191 - y) * N + (191 - x)], outT[row * XP + xt]);
        }
    }
}

extern "C" void kernel_launch(void* const* d_in, const int* in_sizes, int n_in,
                              void* d_out, int out_size, void* d_ws, size_t ws_size,
                              hipStream_t stream) {
    const float* fr = (const float*)d_in[0];
    const float* fi = (const float*)d_in[1];
    const float* zp = (const float*)d_in[2];

    uint32_t* Abf = (uint32_t*)d_ws;                   // 384*384 u32 = 576 KB
    uint32_t* Wt  = Abf + 384 * 384;                   // 192*192 u32 = 144 KB

    prep_kernel<<<576, 256, 0, stream>>>(fr, fi, zp, Abf, Wt, (float*)d_out);
    s1_kernel<<<dim3(6 * NCHUNK, 3), 256, 0, stream>>>(Abf, Wt, (float*)d_out);
}

// Round 10
// 27.285 us; speedup vs baseline: 2.2339x; 1.0855x over previous
//
#include <hip/hip_runtime.h>

#define N 192
#define CCHUNK 8              // c columns per s1 block (B-frag reuse)
#define NCHUNK 28             // 224 / 8 chunks of c per db
#define XT 39                 // x-tile width per block (32 + CCHUNK - 1)
#define XP 41                 // x-tile LDS pitch (f32) - conflict spreading

typedef __attribute__((ext_vector_type(8))) short short8;   // 8 bf16
typedef __attribute__((ext_vector_type(4))) float f32x4;

static __device__ __forceinline__ unsigned short f2bf(float x) {
    uint32_t u = __builtin_bit_cast(uint32_t, x);
    u += 0x7FFFu + ((u >> 16) & 1u);          // RNE (inputs finite)
    return (unsigned short)(u >> 16);
}

// ---------------------------------------------------------------------------
// prep: Abf[r][c] 384x384 packed (bf16 Ar, bf16 -Ai), zero-padded row/col 383;
//       Wt[dx][dy] packed (bf16 Wr, bf16 Wi); zero d_out (atomic target).
// amp = cos(atan2(rho,z))/R = z/(r2+z^2); ph = (2pi/0.5)*R.
// ---------------------------------------------------------------------------
__global__ __launch_bounds__(256) void prep_kernel(const float* __restrict__ fr,
                                                   const float* __restrict__ fi,
                                                   const float* __restrict__ zp,
                                                   uint32_t* __restrict__ Abf,
                                                   uint32_t* __restrict__ Wt,
                                                   float* __restrict__ out) {
    int idx = blockIdx.x * 256 + threadIdx.x;
    float z = zp[0];
    if (idx < 384 * 384) {
        int r = idx / 384, c = idx - r * 384;
        uint32_t pack = 0u;
        if (r < 383 && c < 383) {
            const float X0 = 191.00005f;      // 0.5*(2*192 + 1e-4) - 1
            float xr = (float)r - X0;
            float yc = (float)c - X0;
            float r2 = xr * xr + yc * yc;
            float R2 = r2 + z * z;
            float R  = sqrtf(R2);
            float amp = z / R2;
            float ph = 12.566371f * R;        // 2*pi/0.5
            float sv, cv;
            sincosf(ph, &sv, &cv);
            pack = (uint32_t)f2bf(amp * cv) | ((uint32_t)f2bf(-amp * sv) << 16);
        }
        Abf[idx] = pack;
    }
    if (idx < N * N) {
        int dy = idx / N, dx = idx - dy * N;
        Wt[dx * N + dy] = (uint32_t)f2bf(fr[idx]) | ((uint32_t)f2bf(fi[idx]) << 16);
        out[idx] = 0.f;                       // zero the atomic target each call
    }
}

// ---------------------------------------------------------------------------
// stage 1: G[c][y][dx] = sum_dy Ar[y+dy][c]*Wr[dy][dx] - Ai[y+dy][c]*Wi[dy][dx]
// via mfma_f32_16x16x32_bf16 (K=384); dx-contraction folded in-block into LDS
// f32 tile outT[64][39] (x = c - dx), flushed once per block with atomicAdd
// into flipped d_out.
// A columns staged as 16B quads (elems i..i+3 at slot i), TWO columns per
// buffer -> barrier per 2 c's. __launch_bounds__(256,3) caps VGPR at 168
// -> 3 waves/SIMD to hide the LDS-read-bound inner loop.
// Block = (db, chunk of 8 c's, y-third of 64 rows), 4 waves = 4 y-tiles.
// ---------------------------------------------------------------------------
__global__ __launch_bounds__(256, 3) void s1_kernel(const uint32_t* __restrict__ Abf,
                                                    const uint32_t* __restrict__ Wt,
                                                    float* __restrict__ out) {
    __shared__ uint4 colAq[2][2][384];        // [buf][col-of-pair][slot] 24.6 KB
    __shared__ float outT[64 * XP];           // 10.5 KB per-block output tile

    const int tid  = threadIdx.x;
    const int l    = tid & 63;
    const int w    = tid >> 6;                // wave -> y-tile within third
    const int db   = blockIdx.x / NCHUNK;
    const int ck   = blockIdx.x - db * NCHUNK;
    const int ci0  = ck * CCHUNK;
    const int dx0  = db * 32;
    const int yoff = blockIdx.y * 64;
    const int m    = l & 15;
    const int kg   = l >> 4;

    // B fragments: loaded once, live in registers for all 8 c's.
    uint4 bfr[2][12];
    #pragma unroll
    for (int t = 0; t < 2; ++t) {
        int dx = dx0 + t * 16 + m;
        #pragma unroll
        for (int ks = 0; ks < 12; ++ks)
            bfr[t][ks] = *(const uint4*)(Wt + dx * N + ks * 16 + kg * 4);
    }

    // zero the output tile
    for (int e = tid; e < 64 * XP; e += 256) outT[e] = 0.f;

    // stage first column pair (rows c0, c0+1 of Abf; A symmetric: row c == col c)
    // slot i = elems i..i+3 (dword-aligned 16B load; slots 381..383 unused).
    {
        const uint32_t* a0 = Abf + (dx0 + ci0) * 384;
        const uint32_t* a1 = Abf + (dx0 + ci0 + 1) * 384;
        for (int i = tid; i < 384; i += 256) {
            uint4 v0, v1;
            __builtin_memcpy(&v0, a0 + i, 16);
            __builtin_memcpy(&v1, a1 + i, 16);
            colAq[0][0][i] = v0;
            colAq[0][1][i] = v1;
        }
    }
    __syncthreads();

    for (int p = 0; p < CCHUNK; p += 2) {
        const int cur = (p >> 1) & 1;
        // prefetch next column pair into the other buffer
        if (p < CCHUNK - 2) {
            const uint32_t* a0 = Abf + (dx0 + ci0 + p + 2) * 384;
            const uint32_t* a1 = Abf + (dx0 + ci0 + p + 3) * 384;
            for (int i = tid; i < 384; i += 256) {
                uint4 v0, v1;
                __builtin_memcpy(&v0, a0 + i, 16);
                __builtin_memcpy(&v1, a1 + i, 16);
                colAq[cur ^ 1][0][i] = v0;
                colAq[cur ^ 1][1][i] = v1;
            }
        }

        #pragma unroll
        for (int h = 0; h < 2; ++h) {
            const int q  = p + h;
            const int ci = ci0 + q;
            f32x4 acc0 = {0.f, 0.f, 0.f, 0.f};
            f32x4 acc1 = {0.f, 0.f, 0.f, 0.f};
            const int srow = yoff + w * 16 + m;
            #pragma unroll
            for (int ks = 0; ks < 12; ++ks) {
                int s = srow + ks * 16 + kg * 4;      // <= 379
                uint4 aq = colAq[cur][h][s];          // elems s..s+3, one b128
                union { uint4 q4; short8 v; } af, b0, b1;
                af.q4 = aq;
                b0.q4 = bfr[0][ks]; b1.q4 = bfr[1][ks];
                acc0 = __builtin_amdgcn_mfma_f32_16x16x32_bf16(af.v, b0.v, acc0, 0, 0, 0);
                acc1 = __builtin_amdgcn_mfma_f32_16x16x32_bf16(af.v, b1.v, acc1, 0, 0, 0);
            }

            // fold dx-contraction: lane m holds dx0+m (acc0), dx0+16+m (acc1);
            // x = c - dx -> xt = (q+31) - m and (q+15) - m, all in [0, 39).
            // Rows disjoint per (w, kg) -> no races; waves own their 16 rows.
            if (ci < 223) {
                const int xb = q + 31;
                #pragma unroll
                for (int r = 0; r < 4; ++r) {
                    int row = w * 16 + kg * 4 + r;
                    outT[row * XP + xb - m]      += acc0[r];
                    outT[row * XP + xb - 16 - m] += acc1[r];
                }
            }
        }
        __syncthreads();   // colAq[cur^1] staged this iter is read next iter
    }

    // flush: outT -> flipped d_out (global atomics; ~30 contributors/element)
    const int xg0 = ci0 - 31;
    for (int e = tid; e < 64 * XT; e += 256) {
        int row = e / XT, xt = e - row * XT;
        int x = xg0 + xt;
        if (x >= 0 && x < N) {
            int y = yoff + row;
            atomicAdd(&out[(191 - y) * N + (191 - x)], outT[row * XP + xt]);
        }
    }
}

extern "C" void kernel_launch(void* const* d_in, const int* in_sizes, int n_in,
                              void* d_out, int out_size, void* d_ws, size_t ws_size,
                              hipStream_t stream) {
    const float* fr = (const float*)d_in[0];
    const float* fi = (const float*)d_in[1];
    const float* zp = (const float*)d_in[2];

    uint32_t* Abf = (uint32_t*)d_ws;                   // 384*384 u32 = 576 KB
    uint32_t* Wt  = Abf + 384 * 384;                   // 192*192 u32 = 144 KB

    prep_kernel<<<576, 256, 0, stream>>>(fr, fi, zp, Abf, Wt, (float*)d_out);
    s1_kernel<<<dim3(6 * NCHUNK, 3), 256, 0, stream>>>(Abf, Wt, (float*)d_out);
}